// Round 6
// baseline (648.074 us; speedup 1.0000x reference)
//
#include <hip/hip_runtime.h>
#include <hip/hip_bf16.h>

#define BATCH 8192
#define NUM_LABELS 8190
#define CURW 2944   // padded cur width (K for level 5)
#define YW   8192   // ybuf row stride

typedef __attribute__((ext_vector_type(4))) float f32x4;
typedef __attribute__((ext_vector_type(8))) short bf16x8;

#define VMCNT(n) asm volatile("s_waitcnt vmcnt(" #n ")" ::: "memory")
#define BAR() do { asm volatile("" ::: "memory"); __builtin_amdgcn_s_barrier(); asm volatile("" ::: "memory"); } while (0)
#define LGKM0() do { asm volatile("s_waitcnt lgkmcnt(0)" ::: "memory"); __builtin_amdgcn_sched_barrier(0); } while (0)

// ---------- helpers ----------
__device__ __forceinline__ unsigned short f2bf(float f) {
  unsigned u = __builtin_bit_cast(unsigned, f);
  unsigned r = u + 0x7fffu + ((u >> 16) & 1u);   // RNE; inputs are finite
  return (unsigned short)(r >> 16);
}
__device__ __forceinline__ float bf2f(unsigned short b) {
  return __builtin_bit_cast(float, (unsigned)b << 16);
}
__device__ __forceinline__ void gload_lds16(const void* g, void* l) {
  __builtin_amdgcn_global_load_lds(
      (const __attribute__((address_space(1))) void*)g,
      (__attribute__((address_space(3))) void*)l,
      16, 0, 0);
}

// ---------- fused x-convert + pad-zeroing ----------
__global__ void k_prep_x(const float* __restrict__ x,
                         unsigned short* __restrict__ xraw,
                         unsigned short* __restrict__ cur) {
  const int TX = BATCH * 768 / 4;
  int i = blockIdx.x * 256 + threadIdx.x;
  if (i < TX) {
    float4 v = ((const float4*)x)[i];
    int e = i * 4;
    int row = e / 768;
    int col = e - row * 768;
    ushort4 a, c;
    a.x = f2bf(v.x); a.y = f2bf(v.y); a.z = f2bf(v.z); a.w = f2bf(v.w);
    c.x = f2bf(fmaxf(v.x, 0.f)); c.y = f2bf(fmaxf(v.y, 0.f));
    c.z = f2bf(fmaxf(v.z, 0.f)); c.w = f2bf(fmaxf(v.w, 0.f));
    *(ushort4*)(xraw + e) = a;
    *(ushort4*)(cur + (size_t)row * CURW + col) = c;
    return;
  }
  int j = i - TX;
  const int PP = 130;
  if (j < BATCH * PP) {
    int row = j / PP, p = j - row * PP;
    int col = p < 58 ? 774 + p : (p < 98 ? 856 + (p - 58) : 992 + (p - 98));
    cur[(size_t)row * CURW + col] = 0;
  }
}

// ---------- padded-col -> real-col map ----------
__device__ __forceinline__ int pad2real(int kp) {
  if (kp < 774)  return kp;
  if (kp < 832)  return -1;
  if (kp < 856)  return 774 + (kp - 832);
  if (kp < 896)  return -1;
  if (kp < 992)  return 798 + (kp - 896);
  if (kp < 1024) return -1;
  if (kp < 1408) return 894 + (kp - 1024);
  return 1278 + (kp - 1408);
}

template<int KPAD, int KREAL, int NREAL>
__device__ __forceinline__ void convW(int rel, const float* __restrict__ W,
                                      unsigned short* __restrict__ Wp) {
  int n = rel / KPAD, kp = rel - n * KPAD;
  int kr = pad2real(kp);
  float v = 0.f;
  if (n < NREAL && kr >= 0) v = W[(size_t)n * KREAL + kr];
  Wp[rel] = f2bf(v);
}

// ---------- all weight conversions + inverse permutation in one launch ----------
__global__ void k_convert_w_all(const float* __restrict__ W0, const float* __restrict__ W1,
                                const float* __restrict__ W2, const float* __restrict__ W3,
                                const float* __restrict__ W4, const float* __restrict__ W5,
                                const int* __restrict__ labels, int* __restrict__ inv,
                                unsigned short* __restrict__ wp) {
  int i = blockIdx.x * 256 + threadIdx.x;
  if (i < NUM_LABELS) inv[labels[i]] = i;
  if (i >= 20963328) return;
  if (i < 319488) {
    if (i < 98304)       convW<768, 768, 6>  (i,          W0, wp);
    else if (i < 204800) convW<832, 774, 24> (i - 98304,  W1, wp + 98304);
    else                 convW<896, 798, 96> (i - 204800, W2, wp + 204800);
  } else {
    if (i < 712704)       convW<1024, 894, 384>  (i - 319488,  W3, wp + 319488);
    else if (i < 2875392) convW<1408, 1278, 1536>(i - 712704,  W4, wp + 712704);
    else                  convW<2944, 2814, 6144>(i - 2875392, W5, wp + 2875392);
  }
}

// ---------- fused levels 0-2 ----------
__global__ __launch_bounds__(256, 2) void k_fused_small(
    const unsigned short* __restrict__ xraw,
    const unsigned short* __restrict__ w0p,
    const unsigned short* __restrict__ w1p,
    const unsigned short* __restrict__ w2p,
    const float* __restrict__ b0, const float* __restrict__ b1,
    const float* __restrict__ b2,
    unsigned short* __restrict__ ybuf,
    unsigned short* __restrict__ cur) {
  __shared__ __align__(16) unsigned short As[32 * 1000];
  const int tid = threadIdx.x;
  const int l = tid & 63, w = tid >> 6;
  const int l15 = l & 15, q8 = (l >> 4) * 8;
  const int row0 = blockIdx.x * 32;
  const int mi = w >> 1;
  const int nj0 = w & 1;

  {
    const int r = tid >> 3, c8 = tid & 7;
    const unsigned short* src = xraw + (size_t)(row0 + r) * 768 + c8 * 96;
    unsigned short* dst = As + r * 1000 + c8 * 96;
#pragma unroll
    for (int i = 0; i < 12; ++i)
      *(bf16x8*)(dst + i * 8) = *(const bf16x8*)(src + i * 8);
    unsigned short* dz = As + r * 1000 + 768 + c8 * 28;
    ushort4 z = {0, 0, 0, 0};
#pragma unroll
    for (int i = 0; i < 7; ++i) *(ushort4*)(dz + i * 4) = z;
  }
  __syncthreads();

  auto level = [&](int K, int ntiles, int Nr, const unsigned short* W, int ldw,
                   const float* bias, int ycol, int ccol) {
    for (int n = nj0; n < ntiles; n += 2) {
      f32x4 acc = {0.f, 0.f, 0.f, 0.f};
      const unsigned short* wrow = W + (size_t)(n * 16 + l15) * ldw + q8;
      const unsigned short* arow = As + (mi * 16 + l15) * 1000 + q8;
#pragma unroll 2
      for (int k0 = 0; k0 < K; k0 += 32) {
        bf16x8 af = *(const bf16x8*)(arow + k0);
        bf16x8 bf = *(const bf16x8*)(wrow + k0);
        acc = __builtin_amdgcn_mfma_f32_16x16x32_bf16(af, bf, acc, 0, 0, 0);
      }
      int col = n * 16 + l15;
      if (col < Nr) {
        float bv = bias[col];
#pragma unroll
        for (int j = 0; j < 4; ++j) {
          int rl = mi * 16 + (l >> 4) * 4 + j;
          float y = acc[j] + bv;
          ybuf[(size_t)(row0 + rl) * YW + ycol + col] = f2bf(y);
          As[rl * 1000 + ccol + col] = f2bf(fmaxf(y, 0.f));
        }
      }
    }
    __syncthreads();
  };

  level(768, 1, 6,  w0p, 768, b0, 0,  768);

  {
    const int r = tid >> 3, c8 = tid & 7;
    unsigned short* p = As + r * 1000 + c8 * 96;
#pragma unroll
    for (int i = 0; i < 12; ++i) {
      bf16x8 v = *(bf16x8*)(p + i * 8);
#pragma unroll
      for (int j = 0; j < 8; ++j)
        if (((unsigned short)v[j]) & 0x8000u) v[j] = 0;
      *(bf16x8*)(p + i * 8) = v;
    }
  }
  __syncthreads();

  level(832, 2, 24, w1p, 832, b1, 6,  832);
  level(896, 6, 96, w2p, 896, b2, 30, 896);

  {
    const int r = tid >> 3, c8 = tid & 7;
    const unsigned short* srcl = As + r * 1000 + 768 + c8 * 28;
    unsigned short* dstg = cur + (size_t)(row0 + r) * CURW + 768 + c8 * 28;
#pragma unroll
    for (int i = 0; i < 7; ++i)
      *(ushort4*)(dstg + i * 4) = *(const ushort4*)(srcl + i * 4);
  }
}

// ---------- level-3 GEMM: 128x128 tile, 4 waves ----------
__global__ __launch_bounds__(256, 2) void k_gemm(
    const unsigned short* __restrict__ A, int lda,
    const unsigned short* __restrict__ B, int ldb,
    const float* __restrict__ bias,
    unsigned short* __restrict__ ybuf,
    unsigned short* __restrict__ curout,
    int K, int Nreal, int yoff, int curoff) {
  __shared__ unsigned short Asmem[128 * 64];
  __shared__ unsigned short Bsmem[128 * 64];
  const int tid = threadIdx.x;
  const int lane = tid & 63;
  const int wid = tid >> 6;
  const int wr = wid >> 1, wc = wid & 1;
  const int brow = blockIdx.x * 128;
  const int bcol = blockIdx.y * 128;

  f32x4 acc[4][4] = {};

  for (int k0 = 0; k0 < K; k0 += 64) {
#pragma unroll
    for (int p = 0; p < 4; ++p) {
      int ch = wid * 4 + p;
      int eo = ch * 512 + lane * 8;
      int r = eo >> 6;
      int col = eo & 63;
      gload_lds16(A + (size_t)(brow + r) * lda + k0 + col, Asmem + ch * 512);
      gload_lds16(B + (size_t)(bcol + r) * ldb + k0 + col, Bsmem + ch * 512);
    }
    __syncthreads();
#pragma unroll
    for (int kk = 0; kk < 2; ++kk) {
      bf16x8 af[4], bfr[4];
      int colk = kk * 32 + (lane >> 4) * 8;
#pragma unroll
      for (int m = 0; m < 4; ++m)
        af[m] = *(const bf16x8*)(Asmem + (wr * 64 + m * 16 + (lane & 15)) * 64 + colk);
#pragma unroll
      for (int n = 0; n < 4; ++n)
        bfr[n] = *(const bf16x8*)(Bsmem + (wc * 64 + n * 16 + (lane & 15)) * 64 + colk);
#pragma unroll
      for (int m = 0; m < 4; ++m)
#pragma unroll
        for (int n = 0; n < 4; ++n)
          acc[m][n] = __builtin_amdgcn_mfma_f32_16x16x32_bf16(af[m], bfr[n], acc[m][n], 0, 0, 0);
    }
    __syncthreads();
  }

#pragma unroll
  for (int n = 0; n < 4; ++n) {
    int col = bcol + wc * 64 + n * 16 + (lane & 15);
    if (col >= Nreal) continue;
    float bv = bias[col];
#pragma unroll
    for (int m = 0; m < 4; ++m) {
#pragma unroll
      for (int j = 0; j < 4; ++j) {
        int row = brow + wr * 64 + m * 16 + (lane >> 4) * 4 + j;
        float y = acc[m][n][j] + bv;
        ybuf[(size_t)row * YW + yoff + col] = f2bf(y);
        if (curout) curout[(size_t)row * CURW + curoff + col] = f2bf(fmaxf(y, 0.f));
      }
    }
  }
}

// ---------- big-level GEMM (levels 4-5): 256x256, 8 waves, 8-phase ----------
// Same schedule/ledger as R5 (verified). Addressing rewritten: precomputed LDS
// read bases (+const imm offsets) and running global row pointers (+128/iter,
// in-iteration K offsets {0,64,128,192} fold into the load imm).
__global__ __launch_bounds__(512, 2) void k_gemm256(
    const unsigned short* __restrict__ A, int lda,
    const unsigned short* __restrict__ B, int ldb,
    const float* __restrict__ bias,
    unsigned short* __restrict__ ybuf,
    unsigned short* __restrict__ curout,
    int K, int yoff, int curoff) {
  __shared__ __align__(16) unsigned short lds[65536];  // 128 KiB
  const int tid = threadIdx.x;
  const int l = tid & 63;
  const int w = tid >> 6;
  const int wr = w >> 2;
  const int wc = w & 3;
  const int l15 = l & 15;
  const int q8 = (l >> 4) * 8;
  const int sx = (l & 7) << 3;
  const int swz = ((l & 7) ^ (l >> 3)) * 8;

  const int bid = blockIdx.x;
  const int im = (bid & 7) * 4 + ((bid >> 3) & 3);
  const int in = bid >> 5;
  const int brow = im * 256, bcol = in * 256;

  // global row pointers (advance +128 elems per iteration)
  const unsigned short* gAr0 = A + (size_t)(brow + w * 8 + (l >> 3)) * lda + swz;
  const unsigned short* gAr1 = gAr0 + (size_t)64 * lda;
  const unsigned short* gAr2 = gAr0 + (size_t)128 * lda;
  const unsigned short* gAr3 = gAr0 + (size_t)192 * lda;
  const unsigned short* gBr0 = B + (size_t)(bcol + w * 8 + (l >> 3)) * ldb + swz;
  const unsigned short* gBr1 = gBr0 + (size_t)64 * ldb;
  const unsigned short* gBr2 = gBr0 + (size_t)128 * ldb;
  const unsigned short* gBr3 = gBr0 + (size_t)192 * ldb;

  // LDS stage destinations (wave-uniform, invariant)
  unsigned short* const dA00 = lds + w * 512;
  unsigned short* const dA01 = lds + 8192 + w * 512;
  unsigned short* const dA10 = lds + 16384 + w * 512;
  unsigned short* const dA11 = lds + 24576 + w * 512;
  unsigned short* const dB00 = lds + 32768 + w * 512;
  unsigned short* const dB01 = lds + 40960 + w * 512;
  unsigned short* const dB10 = lds + 49152 + w * 512;
  unsigned short* const dB11 = lds + 57344 + w * 512;

  // LDS read bases: R + row0*64 + ((kk*32+q8)^sx); all further offsets const
  const int cOff0 = (q8) ^ sx;
  const int cOff1 = (32 + q8) ^ sx;
  const int brB = (wc & 1) * 64;
  const unsigned short* const aB00 = lds + wr * 8192 + l15 * 64 + cOff0;
  const unsigned short* const aB01 = lds + wr * 8192 + l15 * 64 + cOff1;
  const unsigned short* const aB10 = lds + 16384 + wr * 8192 + l15 * 64 + cOff0;
  const unsigned short* const aB11 = lds + 16384 + wr * 8192 + l15 * 64 + cOff1;
  const unsigned short* const bB00 = lds + 32768 + (wc >> 1) * 8192 + (brB + l15) * 64 + cOff0;
  const unsigned short* const bB01 = lds + 32768 + (wc >> 1) * 8192 + (brB + l15) * 64 + cOff1;
  const unsigned short* const bB10 = lds + 49152 + (wc >> 1) * 8192 + (brB + l15) * 64 + cOff0;
  const unsigned short* const bB11 = lds + 49152 + (wc >> 1) * 8192 + (brB + l15) * 64 + cOff1;

  f32x4 acc[8][4] = {};
  bf16x8 aF[2][4], bF[2][4];

  auto stage2 = [&](const unsigned short* glo, const unsigned short* ghi,
                    unsigned short* dst, int koff) {
    gload_lds16(glo + koff, dst);
    gload_lds16(ghi + koff, dst + 4096);
  };
  auto ldA = [&](const unsigned short* b0, const unsigned short* b1, int mhalf) {
#pragma unroll
    for (int m = 0; m < 4; ++m) {
      aF[0][m] = *(const bf16x8*)(b0 + (mhalf * 64 + m * 16) * 64);
      aF[1][m] = *(const bf16x8*)(b1 + (mhalf * 64 + m * 16) * 64);
    }
  };
  auto ldB2 = [&](const unsigned short* b0, const unsigned short* b1, int nbase) {
#pragma unroll
    for (int n = 0; n < 2; ++n) {
      bF[0][nbase + n] = *(const bf16x8*)(b0 + (nbase + n) * 16 * 64);
      bF[1][nbase + n] = *(const bf16x8*)(b1 + (nbase + n) * 16 * 64);
    }
  };
  auto MMA = [&](int mbase, int nbase) {
    __builtin_amdgcn_s_setprio(1);
#pragma unroll
    for (int kk = 0; kk < 2; ++kk)
#pragma unroll
      for (int m = 0; m < 4; ++m)
#pragma unroll
        for (int n = 0; n < 2; ++n)
          acc[mbase + m][nbase + n] = __builtin_amdgcn_mfma_f32_16x16x32_bf16(
              aF[kk][m], bF[kk][nbase + n], acc[mbase + m][nbase + n], 0, 0, 0);
    __builtin_amdgcn_s_setprio(0);
  };

  const int KT = K >> 6;
  const int NT2 = KT >> 1;

  // prologue: t0 complete (8 loads) + t1 partial B0,B1,A0 (6 loads)
  stage2(gBr0, gBr1, dB00, 0);
  stage2(gBr2, gBr3, dB01, 0);
  stage2(gAr0, gAr1, dA00, 0);
  stage2(gAr2, gAr3, dA01, 0);
  stage2(gBr0, gBr1, dB10, 64);
  stage2(gBr2, gBr3, dB11, 64);
  stage2(gAr0, gAr1, dA10, 64);
  VMCNT(6);
  BAR();
  ldB2(bB00, bB01, 0);

  for (int it = 0; it < NT2; ++it) {
    const bool more = (it + 1 < NT2);
    // P1
    ldA(aB00, aB01, 0); stage2(gAr2, gAr3, dA11, 64);
    BAR(); LGKM0(); MMA(0, 0); BAR();
    // P2
    ldB2(bB00, bB01, 2);
    BAR(); LGKM0(); MMA(0, 2); BAR();
    // P3
    ldA(aB00, aB01, 1);
    if (more) stage2(gBr0, gBr1, dB00, 128);
    BAR(); LGKM0(); MMA(4, 0); BAR();
    // P4
    if (more) { stage2(gBr2, gBr3, dB01, 128); stage2(gAr0, gAr1, dA00, 128); VMCNT(6); }
    else      { VMCNT(0); }
    BAR(); LGKM0(); MMA(4, 2); ldB2(bB10, bB11, 0); BAR();
    // P5
    ldA(aB10, aB11, 0);
    if (more) stage2(gAr2, gAr3, dA01, 128);
    BAR(); LGKM0(); MMA(0, 0); BAR();
    // P6
    ldB2(bB10, bB11, 2);
    BAR(); LGKM0(); MMA(0, 2); BAR();
    // P7
    ldA(aB10, aB11, 1);
    if (more) stage2(gBr0, gBr1, dB10, 192);
    BAR(); LGKM0(); MMA(4, 0); BAR();
    // P8
    if (more) { stage2(gBr2, gBr3, dB11, 192); stage2(gAr0, gAr1, dA10, 192); VMCNT(6); }
    BAR(); LGKM0(); MMA(4, 2);
    if (more) ldB2(bB00, bB01, 0);
    BAR();
    gAr0 += 128; gAr1 += 128; gAr2 += 128; gAr3 += 128;
    gBr0 += 128; gBr1 += 128; gBr2 += 128; gBr3 += 128;
  }

  // epilogue
  const int j4 = (l >> 4) * 4;
  float bv[4];
#pragma unroll
  for (int n = 0; n < 4; ++n) bv[n] = bias[bcol + wc * 64 + n * 16 + l15];
#pragma unroll
  for (int m = 0; m < 8; ++m) {
    int rowb = brow + wr * 128 + m * 16 + j4;
#pragma unroll
    for (int j = 0; j < 4; ++j) {
      size_t rbase = (size_t)(rowb + j);
#pragma unroll
      for (int n = 0; n < 4; ++n) {
        int col = bcol + wc * 64 + n * 16 + l15;
        float y = acc[m][n][j] + bv[n];
        ybuf[rbase * YW + yoff + col] = f2bf(y);
        if (curout) curout[rbase * CURW + curoff + col] = f2bf(fmaxf(y, 0.f));
      }
    }
  }
}

// ---------- final gather: grid-stride, 4-way ILP ----------
__global__ void k_gather(const unsigned short* __restrict__ ybuf,
                         const int* __restrict__ inv,
                         float* __restrict__ out) {
  const int half = NUM_LABELS / 2;   // 4095
  const long total = (long)BATCH * half;
  for (long b0 = (long)blockIdx.x * 1024; b0 < total; b0 += (long)gridDim.x * 1024) {
    long i = b0 + threadIdx.x;
#pragma unroll
    for (int u = 0; u < 4; ++u, i += 256) {
      if (i < total) {
        int row = (int)(i / half);
        int c2 = (int)(i - (long)row * half) * 2;
        int2 iv = *(const int2*)(inv + c2);
        const unsigned short* yr = ybuf + (size_t)row * YW;
        float2 v;
        v.x = bf2f(yr[iv.x]);
        v.y = bf2f(yr[iv.y]);
        *(float2*)(out + (size_t)row * NUM_LABELS + c2) = v;
      }
    }
  }
}

// ---------- launch ----------
extern "C" void kernel_launch(void* const* d_in, const int* in_sizes, int n_in,
                              void* d_out, int out_size, void* d_ws, size_t ws_size,
                              hipStream_t stream) {
  const float* x = (const float*)d_in[0];
  const float* W[6];
  const float* bias[6];
  for (int i = 0; i < 6; ++i) {
    W[i] = (const float*)d_in[1 + 2 * i];
    bias[i] = (const float*)d_in[2 + 2 * i];
  }
  const int* labels = (const int*)d_in[13];
  float* out = (float*)d_out;

  char* ws = (char*)d_ws;
  unsigned short* xraw = (unsigned short*)(ws);
  unsigned short* cur  = (unsigned short*)(ws + 12582912);
  unsigned short* wp   = (unsigned short*)(ws + 60817408);
  unsigned short* ybuf = (unsigned short*)(ws + 102744064);
  int* inv             = (int*)(ws + 236961792);

  static const int Kpad[6]   = {768, 832, 896, 1024, 1408, 2944};
  static const int Nreal[6]  = {6, 24, 96, 384, 1536, 6144};
  static const int Npad[6]   = {128, 128, 128, 384, 1536, 6144};
  static const size_t woff[6] = {0, 98304, 204800, 319488, 712704, 2875392};
  static const int yoff[6]   = {0, 6, 30, 126, 510, 2046};
  static const int curoff[6] = {768, 832, 896, 1024, 1408, 0};

  {
    int tot = BATCH * 768 / 4 + BATCH * 130;
    k_prep_x<<<(tot + 255) / 256, 256, 0, stream>>>(x, xraw, cur);
  }
  k_convert_w_all<<<(20963328 + 255) / 256, 256, 0, stream>>>(
      W[0], W[1], W[2], W[3], W[4], W[5], labels, inv, wp);

  // levels 0-2 fused
  k_fused_small<<<BATCH / 32, 256, 0, stream>>>(
      xraw, wp + woff[0], wp + woff[1], wp + woff[2],
      bias[0], bias[1], bias[2], ybuf, cur);

  // level 3: 128^2 kernel
  {
    dim3 grid(BATCH / 128, Npad[3] / 128);
    k_gemm<<<grid, 256, 0, stream>>>(cur, CURW, wp + woff[3], Kpad[3], bias[3], ybuf,
                                     cur, Kpad[3], Nreal[3], yoff[3], curoff[3]);
  }
  // levels 4-5: 256^2 8-phase kernel, 2D-XCD decode
  for (int i = 4; i < 6; ++i) {
    int nwg = (BATCH / 256) * (Npad[i] / 256);
    k_gemm256<<<nwg, 512, 0, stream>>>(cur, CURW, wp + woff[i], Kpad[i], bias[i], ybuf,
                                       (i < 5) ? cur : (unsigned short*)nullptr,
                                       Kpad[i], yoff[i], curoff[i]);
  }

  k_gather<<<8192, 256, 0, stream>>>(ybuf, inv, out);
}

// Round 7
// 607.232 us; speedup vs baseline: 1.0673x; 1.0673x over previous
//
#include <hip/hip_runtime.h>
#include <hip/hip_bf16.h>

#define BATCH 8192
#define NUM_LABELS 8190
#define CURW 2944   // padded cur width (K for level 5)
#define YW   8192   // ybuf row stride

typedef __attribute__((ext_vector_type(4))) float f32x4;
typedef __attribute__((ext_vector_type(8))) short bf16x8;

#define VMCNT(n) asm volatile("s_waitcnt vmcnt(" #n ")" ::: "memory")
#define BAR() do { asm volatile("" ::: "memory"); __builtin_amdgcn_s_barrier(); asm volatile("" ::: "memory"); } while (0)
#define WAITK(n) do { asm volatile("s_waitcnt lgkmcnt(" #n ")" ::: "memory"); __builtin_amdgcn_sched_barrier(0); } while (0)

// ---------- helpers ----------
__device__ __forceinline__ unsigned short f2bf(float f) {
  unsigned u = __builtin_bit_cast(unsigned, f);
  unsigned r = u + 0x7fffu + ((u >> 16) & 1u);   // RNE; inputs are finite
  return (unsigned short)(r >> 16);
}
__device__ __forceinline__ float bf2f(unsigned short b) {
  return __builtin_bit_cast(float, (unsigned)b << 16);
}
__device__ __forceinline__ void gload_lds16(const void* g, void* l) {
  __builtin_amdgcn_global_load_lds(
      (const __attribute__((address_space(1))) void*)g,
      (__attribute__((address_space(3))) void*)l,
      16, 0, 0);
}

// ---------- fused x-convert + pad-zeroing ----------
__global__ void k_prep_x(const float* __restrict__ x,
                         unsigned short* __restrict__ xraw,
                         unsigned short* __restrict__ cur) {
  const int TX = BATCH * 768 / 4;
  int i = blockIdx.x * 256 + threadIdx.x;
  if (i < TX) {
    float4 v = ((const float4*)x)[i];
    int e = i * 4;
    int row = e / 768;
    int col = e - row * 768;
    ushort4 a, c;
    a.x = f2bf(v.x); a.y = f2bf(v.y); a.z = f2bf(v.z); a.w = f2bf(v.w);
    c.x = f2bf(fmaxf(v.x, 0.f)); c.y = f2bf(fmaxf(v.y, 0.f));
    c.z = f2bf(fmaxf(v.z, 0.f)); c.w = f2bf(fmaxf(v.w, 0.f));
    *(ushort4*)(xraw + e) = a;
    *(ushort4*)(cur + (size_t)row * CURW + col) = c;
    return;
  }
  int j = i - TX;
  const int PP = 130;
  if (j < BATCH * PP) {
    int row = j / PP, p = j - row * PP;
    int col = p < 58 ? 774 + p : (p < 98 ? 856 + (p - 58) : 992 + (p - 98));
    cur[(size_t)row * CURW + col] = 0;
  }
}

// ---------- padded-col -> real-col map ----------
__device__ __forceinline__ int pad2real(int kp) {
  if (kp < 774)  return kp;
  if (kp < 832)  return -1;
  if (kp < 856)  return 774 + (kp - 832);
  if (kp < 896)  return -1;
  if (kp < 992)  return 798 + (kp - 896);
  if (kp < 1024) return -1;
  if (kp < 1408) return 894 + (kp - 1024);
  return 1278 + (kp - 1408);
}

template<int KPAD, int KREAL, int NREAL>
__device__ __forceinline__ void convW(int rel, const float* __restrict__ W,
                                      unsigned short* __restrict__ Wp) {
  int n = rel / KPAD, kp = rel - n * KPAD;
  int kr = pad2real(kp);
  float v = 0.f;
  if (n < NREAL && kr >= 0) v = W[(size_t)n * KREAL + kr];
  Wp[rel] = f2bf(v);
}

// ---------- all weight conversions + inverse permutation in one launch ----------
__global__ void k_convert_w_all(const float* __restrict__ W0, const float* __restrict__ W1,
                                const float* __restrict__ W2, const float* __restrict__ W3,
                                const float* __restrict__ W4, const float* __restrict__ W5,
                                const int* __restrict__ labels, int* __restrict__ inv,
                                unsigned short* __restrict__ wp) {
  int i = blockIdx.x * 256 + threadIdx.x;
  if (i < NUM_LABELS) inv[labels[i]] = i;
  if (i >= 20963328) return;
  if (i < 319488) {
    if (i < 98304)       convW<768, 768, 6>  (i,          W0, wp);
    else if (i < 204800) convW<832, 774, 24> (i - 98304,  W1, wp + 98304);
    else                 convW<896, 798, 96> (i - 204800, W2, wp + 204800);
  } else {
    if (i < 712704)       convW<1024, 894, 384>  (i - 319488,  W3, wp + 319488);
    else if (i < 2875392) convW<1408, 1278, 1536>(i - 712704,  W4, wp + 712704);
    else                  convW<2944, 2814, 6144>(i - 2875392, W5, wp + 2875392);
  }
}

// ---------- fused levels 0-2 ----------
__global__ __launch_bounds__(256, 2) void k_fused_small(
    const unsigned short* __restrict__ xraw,
    const unsigned short* __restrict__ w0p,
    const unsigned short* __restrict__ w1p,
    const unsigned short* __restrict__ w2p,
    const float* __restrict__ b0, const float* __restrict__ b1,
    const float* __restrict__ b2,
    unsigned short* __restrict__ ybuf,
    unsigned short* __restrict__ cur) {
  __shared__ __align__(16) unsigned short As[32 * 1000];
  const int tid = threadIdx.x;
  const int l = tid & 63, w = tid >> 6;
  const int l15 = l & 15, q8 = (l >> 4) * 8;
  const int row0 = blockIdx.x * 32;
  const int mi = w >> 1;
  const int nj0 = w & 1;

  {
    const int r = tid >> 3, c8 = tid & 7;
    const unsigned short* src = xraw + (size_t)(row0 + r) * 768 + c8 * 96;
    unsigned short* dst = As + r * 1000 + c8 * 96;
#pragma unroll
    for (int i = 0; i < 12; ++i)
      *(bf16x8*)(dst + i * 8) = *(const bf16x8*)(src + i * 8);
    unsigned short* dz = As + r * 1000 + 768 + c8 * 28;
    ushort4 z = {0, 0, 0, 0};
#pragma unroll
    for (int i = 0; i < 7; ++i) *(ushort4*)(dz + i * 4) = z;
  }
  __syncthreads();

  auto level = [&](int K, int ntiles, int Nr, const unsigned short* W, int ldw,
                   const float* bias, int ycol, int ccol) {
    for (int n = nj0; n < ntiles; n += 2) {
      f32x4 acc = {0.f, 0.f, 0.f, 0.f};
      const unsigned short* wrow = W + (size_t)(n * 16 + l15) * ldw + q8;
      const unsigned short* arow = As + (mi * 16 + l15) * 1000 + q8;
#pragma unroll 2
      for (int k0 = 0; k0 < K; k0 += 32) {
        bf16x8 af = *(const bf16x8*)(arow + k0);
        bf16x8 bf = *(const bf16x8*)(wrow + k0);
        acc = __builtin_amdgcn_mfma_f32_16x16x32_bf16(af, bf, acc, 0, 0, 0);
      }
      int col = n * 16 + l15;
      if (col < Nr) {
        float bv = bias[col];
#pragma unroll
        for (int j = 0; j < 4; ++j) {
          int rl = mi * 16 + (l >> 4) * 4 + j;
          float y = acc[j] + bv;
          ybuf[(size_t)(row0 + rl) * YW + ycol + col] = f2bf(y);
          As[rl * 1000 + ccol + col] = f2bf(fmaxf(y, 0.f));
        }
      }
    }
    __syncthreads();
  };

  level(768, 1, 6,  w0p, 768, b0, 0,  768);

  {
    const int r = tid >> 3, c8 = tid & 7;
    unsigned short* p = As + r * 1000 + c8 * 96;
#pragma unroll
    for (int i = 0; i < 12; ++i) {
      bf16x8 v = *(bf16x8*)(p + i * 8);
#pragma unroll
      for (int j = 0; j < 8; ++j)
        if (((unsigned short)v[j]) & 0x8000u) v[j] = 0;
      *(bf16x8*)(p + i * 8) = v;
    }
  }
  __syncthreads();

  level(832, 2, 24, w1p, 832, b1, 6,  832);
  level(896, 6, 96, w2p, 896, b2, 30, 896);

  {
    const int r = tid >> 3, c8 = tid & 7;
    const unsigned short* srcl = As + r * 1000 + 768 + c8 * 28;
    unsigned short* dstg = cur + (size_t)(row0 + r) * CURW + 768 + c8 * 28;
#pragma unroll
    for (int i = 0; i < 7; ++i)
      *(ushort4*)(dstg + i * 4) = *(const ushort4*)(srcl + i * 4);
  }
}

// ---------- level-3 GEMM: 128x128 tile, 4 waves ----------
__global__ __launch_bounds__(256, 2) void k_gemm(
    const unsigned short* __restrict__ A, int lda,
    const unsigned short* __restrict__ B, int ldb,
    const float* __restrict__ bias,
    unsigned short* __restrict__ ybuf,
    unsigned short* __restrict__ curout,
    int K, int Nreal, int yoff, int curoff) {
  __shared__ unsigned short Asmem[128 * 64];
  __shared__ unsigned short Bsmem[128 * 64];
  const int tid = threadIdx.x;
  const int lane = tid & 63;
  const int wid = tid >> 6;
  const int wr = wid >> 1, wc = wid & 1;
  const int brow = blockIdx.x * 128;
  const int bcol = blockIdx.y * 128;

  f32x4 acc[4][4] = {};

  for (int k0 = 0; k0 < K; k0 += 64) {
#pragma unroll
    for (int p = 0; p < 4; ++p) {
      int ch = wid * 4 + p;
      int eo = ch * 512 + lane * 8;
      int r = eo >> 6;
      int col = eo & 63;
      gload_lds16(A + (size_t)(brow + r) * lda + k0 + col, Asmem + ch * 512);
      gload_lds16(B + (size_t)(bcol + r) * ldb + k0 + col, Bsmem + ch * 512);
    }
    __syncthreads();
#pragma unroll
    for (int kk = 0; kk < 2; ++kk) {
      bf16x8 af[4], bfr[4];
      int colk = kk * 32 + (lane >> 4) * 8;
#pragma unroll
      for (int m = 0; m < 4; ++m)
        af[m] = *(const bf16x8*)(Asmem + (wr * 64 + m * 16 + (lane & 15)) * 64 + colk);
#pragma unroll
      for (int n = 0; n < 4; ++n)
        bfr[n] = *(const bf16x8*)(Bsmem + (wc * 64 + n * 16 + (lane & 15)) * 64 + colk);
#pragma unroll
      for (int m = 0; m < 4; ++m)
#pragma unroll
        for (int n = 0; n < 4; ++n)
          acc[m][n] = __builtin_amdgcn_mfma_f32_16x16x32_bf16(af[m], bfr[n], acc[m][n], 0, 0, 0);
    }
    __syncthreads();
  }

#pragma unroll
  for (int n = 0; n < 4; ++n) {
    int col = bcol + wc * 64 + n * 16 + (lane & 15);
    if (col >= Nreal) continue;
    float bv = bias[col];
#pragma unroll
    for (int m = 0; m < 4; ++m) {
#pragma unroll
      for (int j = 0; j < 4; ++j) {
        int row = brow + wr * 64 + m * 16 + (lane >> 4) * 4 + j;
        float y = acc[m][n][j] + bv;
        ybuf[(size_t)row * YW + yoff + col] = f2bf(y);
        if (curout) curout[(size_t)row * CURW + curoff + col] = f2bf(fmaxf(y, 0.f));
      }
    }
  }
}

// ---------- big-level GEMM (levels 4-5): 256x256, 8 waves ----------
// R5 staging ledger unchanged. NEW: per phase, all ds_reads issue up front,
// then a counted-lgkm MFMA ladder overlaps LDS pipe with matrix pipe.
// B01 fragments preloaded at P4/P8 right after the publish barrier.
// Correctness does not depend on WAITK counts (compiler inserts precise
// dep-waits); cross-wave read-vs-restage hazards keep >=1 barrier separation.
__global__ __launch_bounds__(512, 2) void k_gemm256(
    const unsigned short* __restrict__ A, int lda,
    const unsigned short* __restrict__ B, int ldb,
    const float* __restrict__ bias,
    unsigned short* __restrict__ ybuf,
    unsigned short* __restrict__ curout,
    int K, int yoff, int curoff) {
  __shared__ __align__(16) unsigned short lds[65536];  // 128 KiB
  const int tid = threadIdx.x;
  const int l = tid & 63;
  const int w = tid >> 6;
  const int wr = w >> 2;
  const int wc = w & 3;
  const int l15 = l & 15;
  const int q8 = (l >> 4) * 8;
  const int sx = (l & 7) << 3;
  const int swz = ((l & 7) ^ (l >> 3)) * 8;

  const int bid = blockIdx.x;
  const int im = (bid & 7) * 4 + ((bid >> 3) & 3);
  const int in = bid >> 5;
  const int brow = im * 256, bcol = in * 256;

  const unsigned short* gAr0 = A + (size_t)(brow + w * 8 + (l >> 3)) * lda + swz;
  const unsigned short* gAr1 = gAr0 + (size_t)64 * lda;
  const unsigned short* gAr2 = gAr0 + (size_t)128 * lda;
  const unsigned short* gAr3 = gAr0 + (size_t)192 * lda;
  const unsigned short* gBr0 = B + (size_t)(bcol + w * 8 + (l >> 3)) * ldb + swz;
  const unsigned short* gBr1 = gBr0 + (size_t)64 * ldb;
  const unsigned short* gBr2 = gBr0 + (size_t)128 * ldb;
  const unsigned short* gBr3 = gBr0 + (size_t)192 * ldb;

  unsigned short* const dA00 = lds + w * 512;
  unsigned short* const dA01 = lds + 8192 + w * 512;
  unsigned short* const dA10 = lds + 16384 + w * 512;
  unsigned short* const dA11 = lds + 24576 + w * 512;
  unsigned short* const dB00 = lds + 32768 + w * 512;
  unsigned short* const dB01 = lds + 40960 + w * 512;
  unsigned short* const dB10 = lds + 49152 + w * 512;
  unsigned short* const dB11 = lds + 57344 + w * 512;

  const int cOff0 = (q8) ^ sx;
  const int cOff1 = (32 + q8) ^ sx;
  const int brB = (wc & 1) * 64;
  const unsigned short* const aB00 = lds + wr * 8192 + l15 * 64 + cOff0;
  const unsigned short* const aB01 = lds + wr * 8192 + l15 * 64 + cOff1;
  const unsigned short* const aB10 = lds + 16384 + wr * 8192 + l15 * 64 + cOff0;
  const unsigned short* const aB11 = lds + 16384 + wr * 8192 + l15 * 64 + cOff1;
  const unsigned short* const bB00 = lds + 32768 + (wc >> 1) * 8192 + (brB + l15) * 64 + cOff0;
  const unsigned short* const bB01 = lds + 32768 + (wc >> 1) * 8192 + (brB + l15) * 64 + cOff1;
  const unsigned short* const bB10 = lds + 49152 + (wc >> 1) * 8192 + (brB + l15) * 64 + cOff0;
  const unsigned short* const bB11 = lds + 49152 + (wc >> 1) * 8192 + (brB + l15) * 64 + cOff1;

  f32x4 acc[8][4] = {};
  bf16x8 aF[2][4], bF[2][4];

  auto stage2 = [&](const unsigned short* glo, const unsigned short* ghi,
                    unsigned short* dst, int koff) {
    gload_lds16(glo + koff, dst);
    gload_lds16(ghi + koff, dst + 4096);
  };
  // issue order: m-outer so pairs (kk0,kk1) of each m are adjacent
  auto ldAh = [&](const unsigned short* lo, const unsigned short* hi, int half) {
#pragma unroll
    for (int m = 0; m < 4; ++m) {
      aF[0][m] = *(const bf16x8*)(lo + (half * 64 + m * 16) * 64);
      aF[1][m] = *(const bf16x8*)(hi + (half * 64 + m * 16) * 64);
    }
  };
  auto ldB01f = [&](const unsigned short* lo, const unsigned short* hi) {
#pragma unroll
    for (int n = 0; n < 2; ++n) {
      bF[0][n] = *(const bf16x8*)(lo + n * 16 * 64);
      bF[1][n] = *(const bf16x8*)(hi + n * 16 * 64);
    }
  };
  auto ldB23f = [&](const unsigned short* lo, const unsigned short* hi) {
#pragma unroll
    for (int n = 2; n < 4; ++n) {
      bF[0][n] = *(const bf16x8*)(lo + n * 16 * 64);
      bF[1][n] = *(const bf16x8*)(hi + n * 16 * 64);
    }
  };
  auto MM4 = [&](int m, int mbase, int nbase) {   // 4 MFMA for one m
#pragma unroll
    for (int kk = 0; kk < 2; ++kk)
#pragma unroll
      for (int n = 0; n < 2; ++n)
        acc[mbase + m][nbase + n] = __builtin_amdgcn_mfma_f32_16x16x32_bf16(
            aF[kk][m], bF[kk][nbase + n], acc[mbase + m][nbase + n], 0, 0, 0);
  };
  auto MMAblk = [&](int mbase, int nbase) {       // 16 MFMA
    __builtin_amdgcn_s_setprio(1);
#pragma unroll
    for (int kk = 0; kk < 2; ++kk)
#pragma unroll
      for (int m = 0; m < 4; ++m)
#pragma unroll
        for (int n = 0; n < 2; ++n)
          acc[mbase + m][nbase + n] = __builtin_amdgcn_mfma_f32_16x16x32_bf16(
              aF[kk][m], bF[kk][nbase + n], acc[mbase + m][nbase + n], 0, 0, 0);
    __builtin_amdgcn_s_setprio(0);
  };

#define LADDER(mb, nb, w0, w1, w2, w3) do { \
    __builtin_amdgcn_s_setprio(1); \
    WAITK(w0); MM4(0, mb, nb); \
    WAITK(w1); MM4(1, mb, nb); \
    WAITK(w2); MM4(2, mb, nb); \
    WAITK(w3); MM4(3, mb, nb); \
    __builtin_amdgcn_s_setprio(0); \
  } while (0)

  const int KT = K >> 6;
  const int NT2 = KT >> 1;

  // prologue: t0 complete (8 loads) + t1 partial B0,B1,A-h0 (6 loads)
  stage2(gBr0, gBr1, dB00, 0);
  stage2(gBr2, gBr3, dB01, 0);
  stage2(gAr0, gAr1, dA00, 0);
  stage2(gAr2, gAr3, dA01, 0);
  stage2(gBr0, gBr1, dB10, 64);
  stage2(gBr2, gBr3, dB11, 64);
  stage2(gAr0, gAr1, dA10, 64);
  VMCNT(6);          // t0 published
  BAR();
  ldB01f(bB00, bB01);   // prime B01@buf0 (4 reads in flight)

  for (int it = 0; it < NT2; ++it) {
    const bool more = (it + 1 < NT2);
    // P1: Ah0@buf0 x B01   (entry: 4 B01 reads outstanding)
    stage2(gAr2, gAr3, dA11, 64);
    ldAh(aB00, aB01, 0);        // 8 reads
    ldB23f(bB00, bB01);         // 4 reads (used P2)
    LADDER(0, 0, 10, 8, 6, 4);
    BAR();
    // P2: Ah0 x B23 (no new reads)
    MMAblk(0, 2);
    BAR();
    // P3: Ah1@buf0 x B01
    if (more) stage2(gBr0, gBr1, dB00, 128);
    ldAh(aB00, aB01, 1);        // 8 reads
    LADDER(4, 0, 6, 4, 2, 0);
    BAR();
    // P4: Ah1 x B23 ; publish buf1@t1; preload B01@buf1
    if (more) { stage2(gBr2, gBr3, dB01, 128); stage2(gAr0, gAr1, dA00, 128); VMCNT(6); }
    else      { VMCNT(0); }
    BAR();
    ldB01f(bB10, bB11);         // 4 reads (used P5/P7)
    MMAblk(4, 2);
    BAR();
    // P5: Ah0@buf1 x B01'
    if (more) stage2(gAr2, gAr3, dA01, 128);
    ldAh(aB10, aB11, 0);
    ldB23f(bB10, bB11);
    LADDER(0, 0, 10, 8, 6, 4);
    BAR();
    // P6: Ah0 x B23'
    MMAblk(0, 2);
    BAR();
    // P7: Ah1@buf1 x B01'
    if (more) stage2(gBr0, gBr1, dB10, 192);
    ldAh(aB10, aB11, 1);
    LADDER(4, 0, 6, 4, 2, 0);
    BAR();
    // P8: Ah1 x B23' ; publish buf0@t2; preload next B01@buf0
    if (more) { stage2(gBr2, gBr3, dB11, 192); stage2(gAr0, gAr1, dA10, 192); VMCNT(6); }
    BAR();
    if (more) ldB01f(bB00, bB01);
    MMAblk(4, 2);
    BAR();
    gAr0 += 128; gAr1 += 128; gAr2 += 128; gAr3 += 128;
    gBr0 += 128; gBr1 += 128; gBr2 += 128; gBr3 += 128;
  }
#undef LADDER

  // epilogue
  const int j4 = (l >> 4) * 4;
  float bv[4];
#pragma unroll
  for (int n = 0; n < 4; ++n) bv[n] = bias[bcol + wc * 64 + n * 16 + l15];
#pragma unroll
  for (int m = 0; m < 8; ++m) {
    int rowb = brow + wr * 128 + m * 16 + j4;
#pragma unroll
    for (int j = 0; j < 4; ++j) {
      size_t rbase = (size_t)(rowb + j);
#pragma unroll
      for (int n = 0; n < 4; ++n) {
        int col = bcol + wc * 64 + n * 16 + l15;
        float y = acc[m][n][j] + bv[n];
        ybuf[rbase * YW + yoff + col] = f2bf(y);
        if (curout) curout[rbase * CURW + curoff + col] = f2bf(fmaxf(y, 0.f));
      }
    }
  }
}

// ---------- final gather: float2 stores (R5 form) ----------
__global__ void k_gather(const unsigned short* __restrict__ ybuf,
                         const int* __restrict__ inv,
                         float* __restrict__ out) {
  const int half = NUM_LABELS / 2;   // 4095
  int i = blockIdx.x * 256 + threadIdx.x;
  if (i >= BATCH * half) return;
  int row = i / half;
  int c2 = (i - row * half) * 2;
  int2 iv = *(const int2*)(inv + c2);
  const unsigned short* yr = ybuf + (size_t)row * YW;
  float2 v;
  v.x = bf2f(yr[iv.x]);
  v.y = bf2f(yr[iv.y]);
  *(float2*)(out + (size_t)row * NUM_LABELS + c2) = v;
}

// ---------- launch ----------
extern "C" void kernel_launch(void* const* d_in, const int* in_sizes, int n_in,
                              void* d_out, int out_size, void* d_ws, size_t ws_size,
                              hipStream_t stream) {
  const float* x = (const float*)d_in[0];
  const float* W[6];
  const float* bias[6];
  for (int i = 0; i < 6; ++i) {
    W[i] = (const float*)d_in[1 + 2 * i];
    bias[i] = (const float*)d_in[2 + 2 * i];
  }
  const int* labels = (const int*)d_in[13];
  float* out = (float*)d_out;

  char* ws = (char*)d_ws;
  unsigned short* xraw = (unsigned short*)(ws);
  unsigned short* cur  = (unsigned short*)(ws + 12582912);
  unsigned short* wp   = (unsigned short*)(ws + 60817408);
  unsigned short* ybuf = (unsigned short*)(ws + 102744064);
  int* inv             = (int*)(ws + 236961792);

  static const int Kpad[6]   = {768, 832, 896, 1024, 1408, 2944};
  static const int Nreal[6]  = {6, 24, 96, 384, 1536, 6144};
  static const int Npad[6]   = {128, 128, 128, 384, 1536, 6144};
  static const size_t woff[6] = {0, 98304, 204800, 319488, 712704, 2875392};
  static const int yoff[6]   = {0, 6, 30, 126, 510, 2046};
  static const int curoff[6] = {768, 832, 896, 1024, 1408, 0};

  {
    int tot = BATCH * 768 / 4 + BATCH * 130;
    k_prep_x<<<(tot + 255) / 256, 256, 0, stream>>>(x, xraw, cur);
  }
  k_convert_w_all<<<(20963328 + 255) / 256, 256, 0, stream>>>(
      W[0], W[1], W[2], W[3], W[4], W[5], labels, inv, wp);

  // levels 0-2 fused
  k_fused_small<<<BATCH / 32, 256, 0, stream>>>(
      xraw, wp + woff[0], wp + woff[1], wp + woff[2],
      bias[0], bias[1], bias[2], ybuf, cur);

  // level 3: 128^2 kernel
  {
    dim3 grid(BATCH / 128, Npad[3] / 128);
    k_gemm<<<grid, 256, 0, stream>>>(cur, CURW, wp + woff[3], Kpad[3], bias[3], ybuf,
                                     cur, Kpad[3], Nreal[3], yoff[3], curoff[3]);
  }
  // levels 4-5: 256^2 kernel, 2D-XCD decode
  for (int i = 4; i < 6; ++i) {
    int nwg = (BATCH / 256) * (Npad[i] / 256);
    k_gemm256<<<nwg, 512, 0, stream>>>(cur, CURW, wp + woff[i], Kpad[i], bias[i], ybuf,
                                       (i < 5) ? cur : (unsigned short*)nullptr,
                                       Kpad[i], yoff[i], curoff[i]);
  }

  k_gather<<<(BATCH * (NUM_LABELS / 2) + 255) / 256, 256, 0, stream>>>(ybuf, inv, out);
}